// Round 12
// baseline (438.033 us; speedup 1.0000x reference)
//
#include <hip/hip_runtime.h>

// Transposed (channel) attention via Gram decomposition, fp32, MI355X.
// b=4, c=256, n=16384.
//   G = X X^T (per batch), s = X 1
//   scores = Wq G Wk^T + u bk^T + bq v^T ; u = Wq s + n bq, v = Wk s
//   P = softmax(scores/16);  M = P Wv;  r = P bv
//   out = M X + r 1^T + x
//
// R7: k_gram retiled 64x128 (1024 blocks, 4/CU) + register-prefetch pipeline;
// k_out BK 8->32 + same pipeline. Same accumulation order as R5/R7 green runs.
// Scratch: Gp/G/WkT/u/v in d_out (fully overwritten by k_out); ws = M/s/r.

#define BB 4
#define CC 256
#define NN 16384
#define NCH 32
#define CHK (NN / NCH) // 512

// ---------------------------------------------------------------------------
// s[b][c] = sum_n X[b][c][n].  Grid: BB*CC blocks x 256 threads.
// ---------------------------------------------------------------------------
__global__ __launch_bounds__(256) void k_rowsum(const float* __restrict__ X,
                                                float* __restrict__ s) {
  const int row = blockIdx.x; // b*CC + c
  const float4* xr = reinterpret_cast<const float4*>(X + (size_t)row * NN);
  float acc = 0.f;
  for (int i = threadIdx.x; i < NN / 4; i += 256) {
    const float4 v = xr[i];
    acc += v.x + v.y + v.z + v.w;
  }
  __shared__ float red[256];
  red[threadIdx.x] = acc;
  __syncthreads();
  for (int off = 128; off > 0; off >>= 1) {
    if (threadIdx.x < off) red[threadIdx.x] += red[threadIdx.x + off];
    __syncthreads();
  }
  if (threadIdx.x == 0) s[row] = red[0];
}

// ---------------------------------------------------------------------------
// WkT[f][d] = Wk[d][f].  Grid: (8,8) x 256 threads, 32x32 LDS tiles.
// ---------------------------------------------------------------------------
__global__ __launch_bounds__(256) void k_wkt(const float* __restrict__ W,
                                             float* __restrict__ WkT) {
  const float* Wk = W + (size_t)CC * CC;
  __shared__ float tile[32][33];
  const int bx = blockIdx.x, by = blockIdx.y;
  const int tx = threadIdx.x & 31, ty = threadIdx.x >> 5; // 32 x 8
#pragma unroll
  for (int r = 0; r < 32; r += 8)
    tile[ty + r][tx] = Wk[(size_t)(by * 32 + ty + r) * CC + bx * 32 + tx];
  __syncthreads();
#pragma unroll
  for (int r = 0; r < 32; r += 8)
    WkT[(size_t)(bx * 32 + ty + r) * CC + by * 32 + tx] = tile[tx][ty + r];
}

// ---------------------------------------------------------------------------
// u[b][c] = dot(Wq[c], s_b) + n*bq[c];  v[b][d] = dot(Wk[d], s_b).
// Grid: BB blocks x 256 threads.
// ---------------------------------------------------------------------------
__global__ __launch_bounds__(256) void k_uv(const float* __restrict__ W,
                                            const float* __restrict__ bias,
                                            const float* __restrict__ s,
                                            float* __restrict__ u,
                                            float* __restrict__ v) {
  const int b = blockIdx.x;
  const int t = threadIdx.x;
  __shared__ float ssm[256];
  ssm[t] = s[b * CC + t];
  __syncthreads();
  const float* wq = W + (size_t)t * CC;
  const float* wk = W + (size_t)CC * CC + (size_t)t * CC;
  float au = 0.f, av = 0.f;
  for (int e = 0; e < CC; e += 4) {
    const float4 a = *reinterpret_cast<const float4*>(wq + e);
    const float4 c = *reinterpret_cast<const float4*>(wk + e);
    au += a.x * ssm[e] + a.y * ssm[e + 1] + a.z * ssm[e + 2] + a.w * ssm[e + 3];
    av += c.x * ssm[e] + c.y * ssm[e + 1] + c.z * ssm[e + 2] + c.w * ssm[e + 3];
  }
  u[b * CC + t] = au + 16384.f * bias[t];
  v[b * CC + t] = av;
}

// ---------------------------------------------------------------------------
// Gram split-K partials: Gp[b][ch][c][d] = sum_{n in chunk} X[c][n]*X[d][n]
// R7: 64x128 tile. Grid: (2, 4, BB*NCH) = 1024 blocks x 256 threads, BK=32,
// register-prefetch software pipeline (next tile's loads issued before MACs).
// ---------------------------------------------------------------------------
__global__ __launch_bounds__(256) void k_gram(const float* __restrict__ X,
                                              float* __restrict__ Gp) {
  const int bz = blockIdx.z;
  const int b = bz >> 5;
  const int ch = bz & 31;
  const int c0 = blockIdx.y * 64;   // 4 c-tiles of 64
  const int d0 = blockIdx.x * 128;  // 2 d-tiles of 128
  const int nb = ch * CHK;
  const float* Xb = X + (size_t)b * CC * NN;

  __shared__ float As[32][64];  // As[k][c]  8 KB
  __shared__ float Bs[32][128]; // Bs[k][d] 16 KB

  const int tid = threadIdx.x;
  const int tm = tid >> 4;  // 0..15
  const int tn = tid & 15;  // 0..15

  // loaders
  const int a_row = tid >> 2;        // 0..63
  const int a_cg = (tid & 3) * 8;    // 0,8,16,24
  const int b_row = tid >> 1;        // 0..127
  const int b_half = (tid & 1) * 16; // 0 or 16

  float acc[4][8];
#pragma unroll
  for (int i = 0; i < 4; ++i)
#pragma unroll
    for (int j = 0; j < 8; ++j) acc[i][j] = 0.f;

  float4 qa[2], ka[4];
  // prologue: loads for k0 = 0
#pragma unroll
  for (int j = 0; j < 2; ++j)
    qa[j] = *reinterpret_cast<const float4*>(
        &Xb[(size_t)(c0 + a_row) * NN + nb + a_cg + j * 4]);
#pragma unroll
  for (int j = 0; j < 4; ++j)
    ka[j] = *reinterpret_cast<const float4*>(
        &Xb[(size_t)(d0 + b_row) * NN + nb + b_half + j * 4]);

  for (int k0 = 0; k0 < CHK; k0 += 32) {
    __syncthreads(); // previous compute done reading LDS
    As[a_cg + 0][a_row] = qa[0].x;
    As[a_cg + 1][a_row] = qa[0].y;
    As[a_cg + 2][a_row] = qa[0].z;
    As[a_cg + 3][a_row] = qa[0].w;
    As[a_cg + 4][a_row] = qa[1].x;
    As[a_cg + 5][a_row] = qa[1].y;
    As[a_cg + 6][a_row] = qa[1].z;
    As[a_cg + 7][a_row] = qa[1].w;
#pragma unroll
    for (int j = 0; j < 4; ++j) {
      Bs[b_half + j * 4 + 0][b_row] = ka[j].x;
      Bs[b_half + j * 4 + 1][b_row] = ka[j].y;
      Bs[b_half + j * 4 + 2][b_row] = ka[j].z;
      Bs[b_half + j * 4 + 3][b_row] = ka[j].w;
    }
    __syncthreads();
    if (k0 + 32 < CHK) { // issue next tile's loads; latency hides under MACs
      const int kn = nb + k0 + 32;
#pragma unroll
      for (int j = 0; j < 2; ++j)
        qa[j] = *reinterpret_cast<const float4*>(
            &Xb[(size_t)(c0 + a_row) * NN + kn + a_cg + j * 4]);
#pragma unroll
      for (int j = 0; j < 4; ++j)
        ka[j] = *reinterpret_cast<const float4*>(
            &Xb[(size_t)(d0 + b_row) * NN + kn + b_half + j * 4]);
    }
#pragma unroll 8
    for (int kk = 0; kk < 32; ++kk) {
      const float4 a0 = *reinterpret_cast<const float4*>(&As[kk][tm * 4]);
      const float4 b0 = *reinterpret_cast<const float4*>(&Bs[kk][tn * 4]);
      const float4 b1 = *reinterpret_cast<const float4*>(&Bs[kk][64 + tn * 4]);
      const float a[4] = {a0.x, a0.y, a0.z, a0.w};
      const float bb[8] = {b0.x, b0.y, b0.z, b0.w, b1.x, b1.y, b1.z, b1.w};
#pragma unroll
      for (int i = 0; i < 4; ++i)
#pragma unroll
        for (int j = 0; j < 8; ++j) acc[i][j] += a[i] * bb[j];
    }
  }

  float* Sb = Gp + (size_t)(b * NCH + ch) * CC * CC;
#pragma unroll
  for (int i = 0; i < 4; ++i) {
    const int rr = c0 + tm * 4 + i;
    float4 v0, v1;
    v0.x = acc[i][0]; v0.y = acc[i][1]; v0.z = acc[i][2]; v0.w = acc[i][3];
    v1.x = acc[i][4]; v1.y = acc[i][5]; v1.z = acc[i][6]; v1.w = acc[i][7];
    *reinterpret_cast<float4*>(&Sb[(size_t)rr * CC + d0 + tn * 4]) = v0;
    *reinterpret_cast<float4*>(&Sb[(size_t)rr * CC + d0 + 64 + tn * 4]) = v1;
  }
}

// ---------------------------------------------------------------------------
// G[b][c][d] = sum_ch Gp[b][ch][c][d].  Grid: BB*CC blocks x 256 threads.
// ---------------------------------------------------------------------------
__global__ __launch_bounds__(256) void k_red(const float* __restrict__ Gp,
                                             float* __restrict__ G) {
  const int b = blockIdx.x >> 8;
  const int c = blockIdx.x & 255;
  const int d = threadIdx.x;
  float acc = 0.f;
  for (int ch = 0; ch < NCH; ++ch)
    acc += Gp[((size_t)(b * NCH + ch) * CC + c) * CC + d];
  G[((size_t)b * CC + c) * CC + d] = acc;
}

// ---------------------------------------------------------------------------
// Row-parallel fused score/softmax/M kernel. Grid: (CC, BB) = 1024 blocks
// x 256 threads. Block (c, b):
//   T_row = Wq[c] * G_b ; S_row = T_row * WkT + u[c]*bk + bq[c]*v ; /16
//   P = softmax(S_row);  M[c] = P * Wv ; r[c] = P . bv
// ---------------------------------------------------------------------------
__global__ __launch_bounds__(256) void k_fused(const float* __restrict__ G,
                                               const float* __restrict__ WkT,
                                               const float* __restrict__ W,
                                               const float* __restrict__ bias,
                                               const float* __restrict__ u,
                                               const float* __restrict__ v,
                                               float* __restrict__ M,
                                               float* __restrict__ r) {
  const int c = blockIdx.x;
  const int b = blockIdx.y;
  const int t = threadIdx.x;
  const int lane = t & 63, wid = t >> 6;
  const float* Gb = G + (size_t)b * CC * CC;
  const float* Wv = W + (size_t)2 * CC * CC;
  const float* bk = bias + CC;
  const float* bv = bias + 2 * CC;

  __shared__ float sa[256];   // Wq row -> P row
  __shared__ float sb2[256];  // T row
  __shared__ float redbuf[4];

  sa[t] = W[(size_t)c * CC + t]; // Wq[c][:]
  __syncthreads();

  // T_row[t] = sum_f Wq[c][f] * G[f][t]
  float acc = 0.f;
#pragma unroll 4
  for (int f = 0; f < CC; ++f) acc += sa[f] * Gb[(size_t)f * CC + t];
  sb2[t] = acc;
  __syncthreads();

  // S_row[t] = sum_f T_row[f] * WkT[f][t] + u[c]*bk[t] + bq[c]*v[t]
  float sacc = 0.f;
#pragma unroll 4
  for (int f = 0; f < CC; ++f) sacc += sb2[f] * WkT[(size_t)f * CC + t];
  const float uu = u[b * CC + c];
  const float bqc = bias[c];
  sacc = (sacc + uu * bk[t] + bqc * v[b * CC + t]) * 0.0625f;

  // block softmax over 256 values (one per thread)
  float mx = sacc;
#pragma unroll
  for (int m = 32; m; m >>= 1) mx = fmaxf(mx, __shfl_xor(mx, m));
  if (lane == 0) redbuf[wid] = mx;
  __syncthreads();
  mx = fmaxf(fmaxf(redbuf[0], redbuf[1]), fmaxf(redbuf[2], redbuf[3]));
  const float ev = __expf(sacc - mx);
  float sum = ev;
#pragma unroll
  for (int m = 32; m; m >>= 1) sum += __shfl_xor(sum, m);
  __syncthreads(); // all reads of redbuf(max) done
  if (lane == 0) redbuf[wid] = sum;
  __syncthreads();
  sum = redbuf[0] + redbuf[1] + redbuf[2] + redbuf[3];
  const float p = ev / sum;

  sa[t] = p; // reuse sa for P row
  // r[c] = sum_d P[d]*bv[d]
  float rloc = p * bv[t];
#pragma unroll
  for (int m = 32; m; m >>= 1) rloc += __shfl_xor(rloc, m);
  __syncthreads(); // P visible; redbuf reads done
  if (lane == 0) redbuf[wid] = rloc;
  __syncthreads();
  if (t == 0) r[b * CC + c] = redbuf[0] + redbuf[1] + redbuf[2] + redbuf[3];

  // M_row[t] = sum_d P[d] * Wv[d][t]
  float macc = 0.f;
#pragma unroll 4
  for (int d = 0; d < CC; ++d) macc += sa[d] * Wv[(size_t)d * CC + t];
  M[((size_t)b * CC + c) * CC + t] = macc;
}

// ---------------------------------------------------------------------------
// out[b][c][n] = sum_d M[b][c][d] X[b][d][n] + r[b][c] + x[b][c][n]
// R7: BK=32 (8 iters) + register-prefetch pipeline.
// Grid: (NN/128, CC/128, BB) = (128, 2, 4) x 256 threads; 128x128 tile.
// ---------------------------------------------------------------------------
__global__ __launch_bounds__(256) void k_out(const float* __restrict__ M,
                                             const float* __restrict__ r,
                                             const float* __restrict__ X,
                                             float* __restrict__ Out) {
  const int b = blockIdx.z;
  const int m0 = blockIdx.y * 128;
  const int n0 = blockIdx.x * 128;
  const float* A = M + (size_t)b * CC * CC;
  const float* Xb = X + (size_t)b * CC * NN;
  float* Ob = Out + (size_t)b * CC * NN;

  __shared__ float As[32][128]; // As[k][m] 16 KB
  __shared__ float Bs[32][128]; // Bs[k][n] 16 KB

  const int tid = threadIdx.x;
  const int tm = tid >> 4;
  const int tn = tid & 15;

  const int a_row = tid >> 1;        // 0..127 (m)
  const int a_half = (tid & 1) * 16; // 0 or 16 (k)
  const int b_row = tid >> 3;        // 0..31 (k)
  const int b_cg = (tid & 7) * 16;   // 0..112 (n)

  float acc[8][8];
#pragma unroll
  for (int i = 0; i < 8; ++i)
#pragma unroll
    for (int j = 0; j < 8; ++j) acc[i][j] = 0.f;

  float4 av[4], bv[4];
#pragma unroll
  for (int j = 0; j < 4; ++j) {
    av[j] = *reinterpret_cast<const float4*>(
        &A[(size_t)(m0 + a_row) * CC + a_half + j * 4]);
    bv[j] = *reinterpret_cast<const float4*>(
        &Xb[(size_t)b_row * NN + n0 + b_cg + j * 4]);
  }

  for (int k0 = 0; k0 < CC; k0 += 32) {
    __syncthreads();
#pragma unroll
    for (int j = 0; j < 4; ++j) { // A transpose-scatter: As[k][m]
      As[a_half + j * 4 + 0][a_row] = av[j].x;
      As[a_half + j * 4 + 1][a_row] = av[j].y;
      As[a_half + j * 4 + 2][a_row] = av[j].z;
      As[a_half + j * 4 + 3][a_row] = av[j].w;
    }
#pragma unroll
    for (int j = 0; j < 4; ++j) // B direct: Bs[k][n]
      *reinterpret_cast<float4*>(&Bs[b_row][b_cg + j * 4]) = bv[j];
    __syncthreads();
    if (k0 + 32 < CC) { // prefetch next K-slab
#pragma unroll
      for (int j = 0; j < 4; ++j) {
        av[j] = *reinterpret_cast<const float4*>(
            &A[(size_t)(m0 + a_row) * CC + k0 + 32 + a_half + j * 4]);
        bv[j] = *reinterpret_cast<const float4*>(
            &Xb[(size_t)(k0 + 32 + b_row) * NN + n0 + b_cg + j * 4]);
      }
    }
#pragma unroll 8
    for (int kk = 0; kk < 32; ++kk) {
      const float4 a0 = *reinterpret_cast<const float4*>(&As[kk][tm * 4]);
      const float4 a1 = *reinterpret_cast<const float4*>(&As[kk][64 + tm * 4]);
      const float4 b0 = *reinterpret_cast<const float4*>(&Bs[kk][tn * 4]);
      const float4 b1 = *reinterpret_cast<const float4*>(&Bs[kk][64 + tn * 4]);
      const float a[8] = {a0.x, a0.y, a0.z, a0.w, a1.x, a1.y, a1.z, a1.w};
      const float bb[8] = {b0.x, b0.y, b0.z, b0.w, b1.x, b1.y, b1.z, b1.w};
#pragma unroll
      for (int i = 0; i < 8; ++i)
#pragma unroll
        for (int j = 0; j < 8; ++j) acc[i][j] += a[i] * bb[j];
    }
  }

#pragma unroll
  for (int i = 0; i < 8; ++i) {
    const int m = m0 + ((i < 4) ? (tm * 4 + i) : (64 + tm * 4 + (i - 4)));
    const float rv = r[b * CC + m];
    const float4 x0 = *reinterpret_cast<const float4*>(&Xb[(size_t)m * NN + n0 + tn * 4]);
    const float4 x1 = *reinterpret_cast<const float4*>(&Xb[(size_t)m * NN + n0 + 64 + tn * 4]);
    float4 v0, v1;
    v0.x = acc[i][0] + rv + x0.x; v0.y = acc[i][1] + rv + x0.y;
    v0.z = acc[i][2] + rv + x0.z; v0.w = acc[i][3] + rv + x0.w;
    v1.x = acc[i][4] + rv + x1.x; v1.y = acc[i][5] + rv + x1.y;
    v1.z = acc[i][6] + rv + x1.z; v1.w = acc[i][7] + rv + x1.w;
    *reinterpret_cast<float4*>(&Ob[(size_t)m * NN + n0 + tn * 4]) = v0;
    *reinterpret_cast<float4*>(&Ob[(size_t)m * NN + n0 + 64 + tn * 4]) = v1;
  }
}

// ---------------------------------------------------------------------------
extern "C" void kernel_launch(void* const* d_in, const int* in_sizes, int n_in,
                              void* d_out, int out_size, void* d_ws, size_t ws_size,
                              hipStream_t stream) {
  const float* x = (const float*)d_in[0];     // [4][256][128][128]
  const float* w = (const float*)d_in[1];     // [768][256]
  const float* bias = (const float*)d_in[2];  // [768]
  float* out = (float*)d_out;

  // Scratch in d_out (64 MB; fully overwritten by k_out at the end):
  float* Gp  = out;                              // 4*32*256*256 = 32 MB
  float* G   = Gp + (size_t)BB * NCH * CC * CC;  // 4*256*256    =  1 MB
  float* WkT = G + (size_t)BB * CC * CC;         // 256*256      = .25 MB
  float* uV  = WkT + (size_t)CC * CC;            // 4*256
  float* vV  = uV + (size_t)BB * CC;             // 4*256
  // Workspace (~1.02 MB): only what k_out / k_fused outputs need.
  float* Mm = (float*)d_ws;                      // 4*256*256
  float* sV = Mm + (size_t)BB * CC * CC;         // 4*256
  float* rV = sV + (size_t)BB * CC;              // 4*256

  k_rowsum<<<BB * CC, 256, 0, stream>>>(x, sV);

  dim3 gt(8, 8);
  k_wkt<<<gt, 256, 0, stream>>>(w, WkT);

  dim3 g2(2, 4, BB * NCH);
  k_gram<<<g2, 256, 0, stream>>>(x, Gp);

  k_red<<<BB * CC, 256, 0, stream>>>(Gp, G);

  k_uv<<<BB, 256, 0, stream>>>(w, bias, sV, uV, vV);

  dim3 gf(CC, BB);
  k_fused<<<gf, 256, 0, stream>>>(G, WkT, w, bias, uV, vV, Mm, rV);

  dim3 g4(NN / 128, CC / 128, BB);
  k_out<<<g4, 256, 0, stream>>>(Mm, rV, x, out);
}

// Round 13
// 293.417 us; speedup vs baseline: 1.4929x; 1.4929x over previous
//
#include <hip/hip_runtime.h>

// Transposed (channel) attention via Gram decomposition, MI355X.
// R13: k_gram and k_out rewritten as split-bf16 MFMA GEMMs
// (x = hi + lo; A*B ~= Ah*Bh + Ah*Bl + Al*Bh, fp32 accumulate).
// 16x16x32 bf16 MFMA; frag maps: A row=lane&15,k=8*(lane>>4)+i;
// B col=lane&15,k=8*(lane>>4)+i; D col=lane&15,row=4*(lane>>4)+r (m89-verified).
// Everything else identical to the green R12 pipeline.

#define BB 4
#define CC 256
#define NN 16384
#define NCH 32
#define CHK (NN / NCH) // 512
#define LP 40          // padded LDS row stride in bf16 (32 used + 8 pad)

typedef __attribute__((ext_vector_type(8))) short bf16x8;
typedef __attribute__((ext_vector_type(4))) float f32x4;

__device__ __forceinline__ unsigned short f2bf(float x) {
  unsigned int u = __float_as_uint(x);
  u += 0x7FFFu + ((u >> 16) & 1u); // RNE
  return (unsigned short)(u >> 16);
}
__device__ __forceinline__ float bf2f(unsigned short b) {
  return __uint_as_float(((unsigned int)b) << 16);
}

// ---------------------------------------------------------------------------
// s[b][c] = sum_n X[b][c][n].  Grid: BB*CC blocks x 256 threads.
// ---------------------------------------------------------------------------
__global__ __launch_bounds__(256) void k_rowsum(const float* __restrict__ X,
                                                float* __restrict__ s) {
  const int row = blockIdx.x;
  const float4* xr = reinterpret_cast<const float4*>(X + (size_t)row * NN);
  float acc = 0.f;
  for (int i = threadIdx.x; i < NN / 4; i += 256) {
    const float4 v = xr[i];
    acc += v.x + v.y + v.z + v.w;
  }
  __shared__ float red[256];
  red[threadIdx.x] = acc;
  __syncthreads();
  for (int off = 128; off > 0; off >>= 1) {
    if (threadIdx.x < off) red[threadIdx.x] += red[threadIdx.x + off];
    __syncthreads();
  }
  if (threadIdx.x == 0) s[row] = red[0];
}

// ---------------------------------------------------------------------------
// WkT[f][d] = Wk[d][f].  Grid: (8,8) x 256 threads.
// ---------------------------------------------------------------------------
__global__ __launch_bounds__(256) void k_wkt(const float* __restrict__ W,
                                             float* __restrict__ WkT) {
  const float* Wk = W + (size_t)CC * CC;
  __shared__ float tile[32][33];
  const int bx = blockIdx.x, by = blockIdx.y;
  const int tx = threadIdx.x & 31, ty = threadIdx.x >> 5;
#pragma unroll
  for (int r = 0; r < 32; r += 8)
    tile[ty + r][tx] = Wk[(size_t)(by * 32 + ty + r) * CC + bx * 32 + tx];
  __syncthreads();
#pragma unroll
  for (int r = 0; r < 32; r += 8)
    WkT[(size_t)(bx * 32 + ty + r) * CC + by * 32 + tx] = tile[tx][ty + r];
}

// ---------------------------------------------------------------------------
// u[b][c] = dot(Wq[c], s_b) + n*bq[c];  v[b][d] = dot(Wk[d], s_b).
// ---------------------------------------------------------------------------
__global__ __launch_bounds__(256) void k_uv(const float* __restrict__ W,
                                            const float* __restrict__ bias,
                                            const float* __restrict__ s,
                                            float* __restrict__ u,
                                            float* __restrict__ v) {
  const int b = blockIdx.x;
  const int t = threadIdx.x;
  __shared__ float ssm[256];
  ssm[t] = s[b * CC + t];
  __syncthreads();
  const float* wq = W + (size_t)t * CC;
  const float* wk = W + (size_t)CC * CC + (size_t)t * CC;
  float au = 0.f, av = 0.f;
  for (int e = 0; e < CC; e += 4) {
    const float4 a = *reinterpret_cast<const float4*>(wq + e);
    const float4 c = *reinterpret_cast<const float4*>(wk + e);
    au += a.x * ssm[e] + a.y * ssm[e + 1] + a.z * ssm[e + 2] + a.w * ssm[e + 3];
    av += c.x * ssm[e] + c.y * ssm[e + 1] + c.z * ssm[e + 2] + c.w * ssm[e + 3];
  }
  u[b * CC + t] = au + 16384.f * bias[t];
  v[b * CC + t] = av;
}

// ---------------------------------------------------------------------------
// Gram split-K via split-bf16 MFMA.
// Gp[b][ch][c][d] = sum_{n in chunk} X[c][n]*X[d][n]
// Grid: (2, 2, BB*NCH) = 512 blocks x 256 threads (4 waves, 64x64 out each).
// 128x128 tile, BK=32 (one 16x16x32 MFMA K-step), register-prefetch pipeline.
// ---------------------------------------------------------------------------
__global__ __launch_bounds__(256) void k_gram(const float* __restrict__ X,
                                              float* __restrict__ Gp) {
  const int bz = blockIdx.z;
  const int b = bz >> 5, ch = bz & 31;
  const int c0 = blockIdx.y * 128, d0 = blockIdx.x * 128;
  const int nb = ch * CHK;
  const float* Xb = X + (size_t)b * CC * NN;

  __shared__ __align__(16) unsigned short Ah[128 * LP], Al[128 * LP];
  __shared__ __align__(16) unsigned short Bh[128 * LP], Bl[128 * LP];

  const int tid = threadIdx.x;
  const int wid = tid >> 6, lane = tid & 63;
  const int fr = lane & 15, kg = lane >> 4;
  const int m0w = (wid & 1) * 64, n0w = (wid >> 1) * 64;
  const int s_row = tid >> 1, s_kc = (tid & 1) * 16;

  f32x4 acc[4][4];
  const f32x4 zz = {0.f, 0.f, 0.f, 0.f};
#pragma unroll
  for (int mf = 0; mf < 4; ++mf)
#pragma unroll
    for (int nf = 0; nf < 4; ++nf) acc[mf][nf] = zz;

  float4 apre[4], bpre[4];
#pragma unroll
  for (int j = 0; j < 4; ++j) {
    apre[j] = *reinterpret_cast<const float4*>(
        &Xb[(size_t)(c0 + s_row) * NN + nb + s_kc + j * 4]);
    bpre[j] = *reinterpret_cast<const float4*>(
        &Xb[(size_t)(d0 + s_row) * NN + nb + s_kc + j * 4]);
  }

  for (int k0 = 0; k0 < CHK; k0 += 32) {
    __syncthreads();
#pragma unroll
    for (int j = 0; j < 4; ++j) {
      ushort4 h, l;
      h.x = f2bf(apre[j].x); l.x = f2bf(apre[j].x - bf2f(h.x));
      h.y = f2bf(apre[j].y); l.y = f2bf(apre[j].y - bf2f(h.y));
      h.z = f2bf(apre[j].z); l.z = f2bf(apre[j].z - bf2f(h.z));
      h.w = f2bf(apre[j].w); l.w = f2bf(apre[j].w - bf2f(h.w));
      *reinterpret_cast<ushort4*>(&Ah[s_row * LP + s_kc + j * 4]) = h;
      *reinterpret_cast<ushort4*>(&Al[s_row * LP + s_kc + j * 4]) = l;
      ushort4 hb, lb;
      hb.x = f2bf(bpre[j].x); lb.x = f2bf(bpre[j].x - bf2f(hb.x));
      hb.y = f2bf(bpre[j].y); lb.y = f2bf(bpre[j].y - bf2f(hb.y));
      hb.z = f2bf(bpre[j].z); lb.z = f2bf(bpre[j].z - bf2f(hb.z));
      hb.w = f2bf(bpre[j].w); lb.w = f2bf(bpre[j].w - bf2f(hb.w));
      *reinterpret_cast<ushort4*>(&Bh[s_row * LP + s_kc + j * 4]) = hb;
      *reinterpret_cast<ushort4*>(&Bl[s_row * LP + s_kc + j * 4]) = lb;
    }
    __syncthreads();
    if (k0 + 32 < CHK) {
      const int kn = nb + k0 + 32;
#pragma unroll
      for (int j = 0; j < 4; ++j) {
        apre[j] = *reinterpret_cast<const float4*>(
            &Xb[(size_t)(c0 + s_row) * NN + kn + s_kc + j * 4]);
        bpre[j] = *reinterpret_cast<const float4*>(
            &Xb[(size_t)(d0 + s_row) * NN + kn + s_kc + j * 4]);
      }
    }
    bf16x8 ah[4], al4[4], bh4[4], bl4[4];
#pragma unroll
    for (int f = 0; f < 4; ++f) {
      ah[f]  = *reinterpret_cast<const bf16x8*>(&Ah[(m0w + f * 16 + fr) * LP + kg * 8]);
      al4[f] = *reinterpret_cast<const bf16x8*>(&Al[(m0w + f * 16 + fr) * LP + kg * 8]);
      bh4[f] = *reinterpret_cast<const bf16x8*>(&Bh[(n0w + f * 16 + fr) * LP + kg * 8]);
      bl4[f] = *reinterpret_cast<const bf16x8*>(&Bl[(n0w + f * 16 + fr) * LP + kg * 8]);
    }
#pragma unroll
    for (int mf = 0; mf < 4; ++mf)
#pragma unroll
      for (int nf = 0; nf < 4; ++nf) {
        acc[mf][nf] = __builtin_amdgcn_mfma_f32_16x16x32_bf16(ah[mf], bh4[nf], acc[mf][nf], 0, 0, 0);
        acc[mf][nf] = __builtin_amdgcn_mfma_f32_16x16x32_bf16(ah[mf], bl4[nf], acc[mf][nf], 0, 0, 0);
        acc[mf][nf] = __builtin_amdgcn_mfma_f32_16x16x32_bf16(al4[mf], bh4[nf], acc[mf][nf], 0, 0, 0);
      }
  }

  float* Sb = Gp + (size_t)(b * NCH + ch) * CC * CC;
#pragma unroll
  for (int mf = 0; mf < 4; ++mf)
#pragma unroll
    for (int nf = 0; nf < 4; ++nf)
#pragma unroll
      for (int rr = 0; rr < 4; ++rr) {
        const int row = c0 + m0w + mf * 16 + kg * 4 + rr;
        const int col = d0 + n0w + nf * 16 + fr;
        Sb[(size_t)row * CC + col] = acc[mf][nf][rr];
      }
}

// ---------------------------------------------------------------------------
// G[b][c][d] = sum_ch Gp[b][ch][c][d].
// ---------------------------------------------------------------------------
__global__ __launch_bounds__(256) void k_red(const float* __restrict__ Gp,
                                             float* __restrict__ G) {
  const int b = blockIdx.x >> 8;
  const int c = blockIdx.x & 255;
  const int d = threadIdx.x;
  float acc = 0.f;
  for (int ch = 0; ch < NCH; ++ch)
    acc += Gp[((size_t)(b * NCH + ch) * CC + c) * CC + d];
  G[((size_t)b * CC + c) * CC + d] = acc;
}

// ---------------------------------------------------------------------------
// Row-parallel fused score/softmax/M kernel (unchanged, green R5/R12).
// ---------------------------------------------------------------------------
__global__ __launch_bounds__(256) void k_fused(const float* __restrict__ G,
                                               const float* __restrict__ WkT,
                                               const float* __restrict__ W,
                                               const float* __restrict__ bias,
                                               const float* __restrict__ u,
                                               const float* __restrict__ v,
                                               float* __restrict__ M,
                                               float* __restrict__ r) {
  const int c = blockIdx.x;
  const int b = blockIdx.y;
  const int t = threadIdx.x;
  const int lane = t & 63, wid = t >> 6;
  const float* Gb = G + (size_t)b * CC * CC;
  const float* Wv = W + (size_t)2 * CC * CC;
  const float* bk = bias + CC;
  const float* bv = bias + 2 * CC;

  __shared__ float sa[256];
  __shared__ float sb2[256];
  __shared__ float redbuf[4];

  sa[t] = W[(size_t)c * CC + t];
  __syncthreads();

  float acc = 0.f;
#pragma unroll 4
  for (int f = 0; f < CC; ++f) acc += sa[f] * Gb[(size_t)f * CC + t];
  sb2[t] = acc;
  __syncthreads();

  float sacc = 0.f;
#pragma unroll 4
  for (int f = 0; f < CC; ++f) sacc += sb2[f] * WkT[(size_t)f * CC + t];
  const float uu = u[b * CC + c];
  const float bqc = bias[c];
  sacc = (sacc + uu * bk[t] + bqc * v[b * CC + t]) * 0.0625f;

  float mx = sacc;
#pragma unroll
  for (int m = 32; m; m >>= 1) mx = fmaxf(mx, __shfl_xor(mx, m));
  if (lane == 0) redbuf[wid] = mx;
  __syncthreads();
  mx = fmaxf(fmaxf(redbuf[0], redbuf[1]), fmaxf(redbuf[2], redbuf[3]));
  const float ev = __expf(sacc - mx);
  float sum = ev;
#pragma unroll
  for (int m = 32; m; m >>= 1) sum += __shfl_xor(sum, m);
  __syncthreads();
  if (lane == 0) redbuf[wid] = sum;
  __syncthreads();
  sum = redbuf[0] + redbuf[1] + redbuf[2] + redbuf[3];
  const float p = ev / sum;

  sa[t] = p;
  float rloc = p * bv[t];
#pragma unroll
  for (int m = 32; m; m >>= 1) rloc += __shfl_xor(rloc, m);
  __syncthreads();
  if (lane == 0) redbuf[wid] = rloc;
  __syncthreads();
  if (t == 0) r[b * CC + c] = redbuf[0] + redbuf[1] + redbuf[2] + redbuf[3];

  float macc = 0.f;
#pragma unroll 4
  for (int d = 0; d < CC; ++d) macc += sa[d] * Wv[(size_t)d * CC + t];
  M[((size_t)b * CC + c) * CC + t] = macc;
}

// ---------------------------------------------------------------------------
// out = M X + r 1^T + x via split-bf16 MFMA.
// Grid: (NN/128, CC/128, BB) = (128, 2, 4) x 256 threads (4 waves, 64x64).
// A = M (m-major, k-contig staging); B = X staged TRANSPOSED [n][k].
// ---------------------------------------------------------------------------
__global__ __launch_bounds__(256) void k_out(const float* __restrict__ M,
                                             const float* __restrict__ r,
                                             const float* __restrict__ X,
                                             float* __restrict__ Out) {
  const int b = blockIdx.z;
  const int m0 = blockIdx.y * 128;
  const int n0 = blockIdx.x * 128;
  const float* A = M + (size_t)b * CC * CC;
  const float* Xb = X + (size_t)b * CC * NN;
  float* Ob = Out + (size_t)b * CC * NN;

  __shared__ __align__(16) unsigned short Mh[128 * LP], Ml[128 * LP];
  __shared__ __align__(16) unsigned short Th[128 * LP], Tl[128 * LP]; // X^T tiles

  const int tid = threadIdx.x;
  const int wid = tid >> 6, lane = tid & 63;
  const int fr = lane & 15, kg = lane >> 4;
  const int m0w = (wid & 1) * 64, n0w = (wid >> 1) * 64;
  const int sa_m = tid >> 1, sa_k = (tid & 1) * 16;  // A stager
  const int sb_d = tid >> 3, sb_n = (tid & 7) * 16;  // B stager (d rows 0..31)

  f32x4 acc[4][4];
  const f32x4 zz = {0.f, 0.f, 0.f, 0.f};
#pragma unroll
  for (int mf = 0; mf < 4; ++mf)
#pragma unroll
    for (int nf = 0; nf < 4; ++nf) acc[mf][nf] = zz;

  float4 apre[4], bpre[4];
#pragma unroll
  for (int j = 0; j < 4; ++j) {
    apre[j] = *reinterpret_cast<const float4*>(
        &A[(size_t)(m0 + sa_m) * CC + sa_k + j * 4]);
    bpre[j] = *reinterpret_cast<const float4*>(
        &Xb[(size_t)sb_d * NN + n0 + sb_n + j * 4]);
  }

  for (int k0 = 0; k0 < CC; k0 += 32) {
    __syncthreads();
#pragma unroll
    for (int j = 0; j < 4; ++j) {
      ushort4 h, l;
      h.x = f2bf(apre[j].x); l.x = f2bf(apre[j].x - bf2f(h.x));
      h.y = f2bf(apre[j].y); l.y = f2bf(apre[j].y - bf2f(h.y));
      h.z = f2bf(apre[j].z); l.z = f2bf(apre[j].z - bf2f(h.z));
      h.w = f2bf(apre[j].w); l.w = f2bf(apre[j].w - bf2f(h.w));
      *reinterpret_cast<ushort4*>(&Mh[sa_m * LP + sa_k + j * 4]) = h;
      *reinterpret_cast<ushort4*>(&Ml[sa_m * LP + sa_k + j * 4]) = l;
      // B transpose-scatter: X[k0+sb_d][n0+sb_n+4j+e] -> T[sb_n+4j+e][sb_d]
      {
        unsigned short hh, ll;
        hh = f2bf(bpre[j].x); ll = f2bf(bpre[j].x - bf2f(hh));
        Th[(sb_n + j * 4 + 0) * LP + sb_d] = hh; Tl[(sb_n + j * 4 + 0) * LP + sb_d] = ll;
        hh = f2bf(bpre[j].y); ll = f2bf(bpre[j].y - bf2f(hh));
        Th[(sb_n + j * 4 + 1) * LP + sb_d] = hh; Tl[(sb_n + j * 4 + 1) * LP + sb_d] = ll;
        hh = f2bf(bpre[j].z); ll = f2bf(bpre[j].z - bf2f(hh));
        Th[(sb_n + j * 4 + 2) * LP + sb_d] = hh; Tl[(sb_n + j * 4 + 2) * LP + sb_d] = ll;
        hh = f2bf(bpre[j].w); ll = f2bf(bpre[j].w - bf2f(hh));
        Th[(sb_n + j * 4 + 3) * LP + sb_d] = hh; Tl[(sb_n + j * 4 + 3) * LP + sb_d] = ll;
      }
    }
    __syncthreads();
    if (k0 + 32 < CC) {
#pragma unroll
      for (int j = 0; j < 4; ++j) {
        apre[j] = *reinterpret_cast<const float4*>(
            &A[(size_t)(m0 + sa_m) * CC + k0 + 32 + sa_k + j * 4]);
        bpre[j] = *reinterpret_cast<const float4*>(
            &Xb[(size_t)(k0 + 32 + sb_d) * NN + n0 + sb_n + j * 4]);
      }
    }
    bf16x8 ah[4], al4[4], bh4[4], bl4[4];
#pragma unroll
    for (int f = 0; f < 4; ++f) {
      ah[f]  = *reinterpret_cast<const bf16x8*>(&Mh[(m0w + f * 16 + fr) * LP + kg * 8]);
      al4[f] = *reinterpret_cast<const bf16x8*>(&Ml[(m0w + f * 16 + fr) * LP + kg * 8]);
      bh4[f] = *reinterpret_cast<const bf16x8*>(&Th[(n0w + f * 16 + fr) * LP + kg * 8]);
      bl4[f] = *reinterpret_cast<const bf16x8*>(&Tl[(n0w + f * 16 + fr) * LP + kg * 8]);
    }
#pragma unroll
    for (int mf = 0; mf < 4; ++mf)
#pragma unroll
      for (int nf = 0; nf < 4; ++nf) {
        acc[mf][nf] = __builtin_amdgcn_mfma_f32_16x16x32_bf16(ah[mf], bh4[nf], acc[mf][nf], 0, 0, 0);
        acc[mf][nf] = __builtin_amdgcn_mfma_f32_16x16x32_bf16(ah[mf], bl4[nf], acc[mf][nf], 0, 0, 0);
        acc[mf][nf] = __builtin_amdgcn_mfma_f32_16x16x32_bf16(al4[mf], bh4[nf], acc[mf][nf], 0, 0, 0);
      }
  }

#pragma unroll
  for (int mf = 0; mf < 4; ++mf)
#pragma unroll
    for (int nf = 0; nf < 4; ++nf)
#pragma unroll
      for (int rr = 0; rr < 4; ++rr) {
        const int m = m0 + m0w + mf * 16 + kg * 4 + rr;
        const int n = n0 + n0w + nf * 16 + fr;
        Ob[(size_t)m * NN + n] =
            acc[mf][nf][rr] + r[b * CC + m] + Xb[(size_t)m * NN + n];
      }
}

// ---------------------------------------------------------------------------
extern "C" void kernel_launch(void* const* d_in, const int* in_sizes, int n_in,
                              void* d_out, int out_size, void* d_ws, size_t ws_size,
                              hipStream_t stream) {
  const float* x = (const float*)d_in[0];     // [4][256][128][128]
  const float* w = (const float*)d_in[1];     // [768][256]
  const float* bias = (const float*)d_in[2];  // [768]
  float* out = (float*)d_out;

  // Scratch in d_out (64 MB; fully overwritten by k_out at the end):
  float* Gp  = out;                              // 32 MB
  float* G   = Gp + (size_t)BB * NCH * CC * CC;  // 1 MB
  float* WkT = G + (size_t)BB * CC * CC;         // .25 MB
  float* uV  = WkT + (size_t)CC * CC;
  float* vV  = uV + (size_t)BB * CC;
  // Workspace (~1.02 MB):
  float* Mm = (float*)d_ws;
  float* sV = Mm + (size_t)BB * CC * CC;
  float* rV = sV + (size_t)BB * CC;

  k_rowsum<<<BB * CC, 256, 0, stream>>>(x, sV);

  dim3 gt(8, 8);
  k_wkt<<<gt, 256, 0, stream>>>(w, WkT);

  dim3 g2(2, 2, BB * NCH);
  k_gram<<<g2, 256, 0, stream>>>(x, Gp);

  k_red<<<BB * CC, 256, 0, stream>>>(Gp, G);

  k_uv<<<BB, 256, 0, stream>>>(w, bias, sV, uV, vV);

  dim3 gf(CC, BB);
  k_fused<<<gf, 256, 0, stream>>>(G, WkT, w, bias, uV, vV, Mm, rV);

  dim3 g4(NN / 128, CC / 128, BB);
  k_out<<<g4, 256, 0, stream>>>(Mm, rV, x, out);
}